// Round 3
// baseline (37679.779 us; speedup 1.0000x reference)
//
#include <hip/hip_runtime.h>
#include <math.h>

#define T_ALL 200
#define G     2048
#define H     512

typedef __attribute__((address_space(1))) const unsigned int g_u32;
typedef __attribute__((address_space(3))) unsigned int l_u32;

__device__ __forceinline__ void gl2lds16(const void* g, void* l) {
    __builtin_amdgcn_global_load_lds((g_u32*)g, (l_u32*)l, 16, 0, 0);
}

__device__ __forceinline__ float sigf(float x) { return 1.0f / (1.0f + expf(-x)); }

// proposals [b][t][c] -> xT[t][c/4][b] (float4 over c)
__global__ __launch_bounds__(256) void transpose_x(const float4* __restrict__ in,
                                                   float4* __restrict__ out) {
    const int t = blockIdx.x;      // 0..199
    const int b = threadIdx.x;     // 0..255
    #pragma unroll 4
    for (int cc = 0; cc < 32; ++cc) {
        out[((size_t)t * 32 + cc) * 256 + b] = in[((size_t)b * 200 + t) * 32 + cc];
    }
}

// xp[tloc][r][b] = bih[r]+bhh[r] + sum_k W[r][k] * x[t][k][b]
// x layout: [t][K4][256] float4 (float4 spans k). grid (len, 4 bg, 64 rchunks), block 256.
__global__ __launch_bounds__(256) void xproj_gemm(
    const float4* __restrict__ x, const float* __restrict__ W,
    const float* __restrict__ bih, const float* __restrict__ bhh,
    float* __restrict__ xp, int K4, int t0)
{
    __shared__ float4 hs[2][2048];   // 2 x 32 KB
    const int tloc = blockIdx.x;
    const int t    = t0 + tloc;
    const int bg   = blockIdx.y;
    const int tid  = threadIdx.x;
    const int wv   = tid >> 6;
    const int lane = tid & 63;
    const int bG   = bg * 64 + lane;
    const int rbase = __builtin_amdgcn_readfirstlane(blockIdx.z * 32 + wv * 8);

    const float* wr[8];
    float a[8];
    #pragma unroll
    for (int i = 0; i < 8; ++i) {
        const int r = rbase + i;
        wr[i] = W + (size_t)r * (K4 * 4);
        a[i] = bih[r] + bhh[r];
    }

    const float4* xt = x + (size_t)t * K4 * 256;
    const int nr = K4 >> 5;   // 1 (K=128) or 4 (K=512)

    #pragma unroll
    for (int j = 0; j < 8; ++j) {
        const int kk = wv + 4 * j;
        gl2lds16(xt + (size_t)kk * 256 + bG, &hs[0][kk * 64]);
    }
    __syncthreads();

    for (int ro = 0; ro < nr; ++ro) {
        if (ro + 1 < nr) {
            #pragma unroll
            for (int j = 0; j < 8; ++j) {
                const int kk = wv + 4 * j;
                gl2lds16(xt + (size_t)((ro + 1) * 32 + kk) * 256 + bG,
                         &hs[(ro + 1) & 1][kk * 64]);
            }
        }
        const float4* hb = hs[ro & 1];
        const int kbase = ro * 32;
        #pragma unroll 4
        for (int kk = 0; kk < 32; ++kk) {
            const float4 v = hb[kk * 64 + lane];
            const int ko = (kbase + kk) * 4;
            #pragma unroll
            for (int i = 0; i < 8; ++i) {
                const float4 w = *(const float4*)(wr[i] + ko);
                a[i] += w.x * v.x + w.y * v.y + w.z * v.z + w.w * v.w;
            }
        }
        __syncthreads();
    }

    #pragma unroll
    for (int i = 0; i < 8; ++i)
        xp[((size_t)tloc * G + rbase + i) * 256 + bG] = a[i];
}

// Recurrent-only LSTM scan. grid (64, 4 bgroups), block 256 = 4 waves.
// Barrier: distributed arrive array (64 slots/group, groups 256B apart),
// single release STORE per block, all waves spin on one coalesced acquire load.
__global__ __launch_bounds__(256) void lstm_scan(
    const float* __restrict__ xp, const float* __restrict__ Wr,
    float4* hbase, float* __restrict__ cbuf,
    int t0, int t1, int tmask, int* arr_base)
{
    __shared__ float4 hs[2][2048];   // 2 x 32 KB double buffer
    const int tid  = threadIdx.x;
    const int wv   = tid >> 6;
    const int lane = tid & 63;
    const int bi   = blockIdx.x;     // 0..63
    const int bg   = blockIdx.y;     // 0..3
    const int bG   = bg * 64 + lane;
    const int hid0 = __builtin_amdgcn_readfirstlane(bi * 8 + wv * 2);
    int* arr = arr_base + bg * 64;   // this group's 64 arrive slots

    const float* wr[8];
    #pragma unroll
    for (int p = 0; p < 2; ++p)
        #pragma unroll
        for (int q = 0; q < 4; ++q)
            wr[p * 4 + q] = Wr + (size_t)(q * H + hid0 + p) * H;

    float c0, c1;
    if (t0 > 0) {
        c0 = cbuf[(size_t)hid0 * 256 + bG];
        c1 = cbuf[(size_t)(hid0 + 1) * 256 + bG];
    } else { c0 = 0.f; c1 = 0.f; }

    // prefetch xp for first step
    float a[8];
    {
        const float* xpt = xp;
        #pragma unroll
        for (int p = 0; p < 2; ++p)
            #pragma unroll
            for (int q = 0; q < 4; ++q)
                a[p * 4 + q] = xpt[(size_t)(q * H + hid0 + p) * 256 + bG];
    }

    for (int t = t0; t < t1; ++t) {
        if (t > 0) {
            const float4* hin = hbase + (size_t)((t - 1) & tmask) * 32768;
            #pragma unroll
            for (int j = 0; j < 8; ++j) {
                const int kk = wv + 4 * j;
                gl2lds16(hin + (size_t)kk * 256 + bG, &hs[0][kk * 64]);
            }
            __syncthreads();
            for (int ro = 0; ro < 4; ++ro) {
                if (ro < 3) {
                    #pragma unroll
                    for (int j = 0; j < 8; ++j) {
                        const int kk = wv + 4 * j;
                        gl2lds16(hin + (size_t)((ro + 1) * 32 + kk) * 256 + bG,
                                 &hs[(ro + 1) & 1][kk * 64]);
                    }
                }
                const float4* hb = hs[ro & 1];
                const int kbase = ro * 32;
                #pragma unroll 4
                for (int kk = 0; kk < 32; ++kk) {
                    const float4 v = hb[kk * 64 + lane];
                    const int ko = (kbase + kk) * 4;
                    #pragma unroll
                    for (int i = 0; i < 8; ++i) {
                        const float4 w = *(const float4*)(wr[i] + ko);
                        a[i] += w.x * v.x + w.y * v.y + w.z * v.z + w.w * v.w;
                    }
                }
                __syncthreads();
            }
        }

        // prefetch next step's xp (independent of h) -- hides behind barrier spin
        float an[8];
        if (t + 1 < t1) {
            const float* xpt = xp + (size_t)(t + 1 - t0) * G * 256;
            #pragma unroll
            for (int p = 0; p < 2; ++p)
                #pragma unroll
                for (int q = 0; q < 4; ++q)
                    an[p * 4 + q] = xpt[(size_t)(q * H + hid0 + p) * 256 + bG];
        }

        const int slot = t & tmask;
        float* hw = (float*)(hbase + (size_t)slot * 32768);
        {
            const float ig = sigf(a[0]), fg = sigf(a[1]);
            const float gg = tanhf(a[2]), og = sigf(a[3]);
            c0 = fg * c0 + ig * gg;
            const float h = og * tanhf(c0);
            hw[(((hid0 >> 2) * 256) + bG) * 4 + (hid0 & 3)] = h;
        }
        {
            const float ig = sigf(a[4]), fg = sigf(a[5]);
            const float gg = tanhf(a[6]), og = sigf(a[7]);
            c1 = fg * c1 + ig * gg;
            const float h = og * tanhf(c1);
            const int h1i = hid0 + 1;
            hw[(((h1i >> 2) * 256) + bG) * 4 + (h1i & 3)] = h;
        }

        if (t + 1 < t1) {
            __threadfence();
            __syncthreads();
            if (tid == 0)
                __hip_atomic_store(&arr[bi], t + 1, __ATOMIC_RELEASE, __HIP_MEMORY_SCOPE_AGENT);
            int v;
            do {
                v = __hip_atomic_load(&arr[lane], __ATOMIC_ACQUIRE, __HIP_MEMORY_SCOPE_AGENT);
            } while (!__all(v >= t + 1));
        }

        #pragma unroll
        for (int i = 0; i < 8; ++i) a[i] = an[i];
    }

    cbuf[(size_t)hid0 * 256 + bG] = c0;
    cbuf[(size_t)(hid0 + 1) * 256 + bG] = c1;
}

// heads: base[k/4][b] (float4 over k) -> cls (256x40), bbox (256x2), 2 zero scalars
__global__ __launch_bounds__(64) void heads(
    const float4* __restrict__ base, const float4* __restrict__ clsW,
    const float* __restrict__ clsb, const float4* __restrict__ bbW,
    const float* __restrict__ bbb, float* __restrict__ out)
{
    const int b = blockIdx.x;    // 0..255
    const int j = threadIdx.x;   // 0..63
    if (j < 42) {
        const float4* w = (j < 40) ? (clsW + (size_t)j * 128) : (bbW + (size_t)(j - 40) * 128);
        float acc = 0.f;
        #pragma unroll 4
        for (int kk = 0; kk < 128; ++kk) {
            const float4 bv = base[(size_t)kk * 256 + b];
            const float4 wv = w[kk];
            acc += bv.x*wv.x + bv.y*wv.y + bv.z*wv.z + bv.w*wv.w;
        }
        if (j < 40) out[(size_t)b * 40 + j] = acc + clsb[j];
        else        out[10240 + (size_t)b * 2 + (j - 40)] = acc + bbb[j - 40];
    }
    if (b == 0 && (j == 62 || j == 63)) out[10752 + (j - 62)] = 0.f;
}

extern "C" void kernel_launch(void* const* d_in, const int* in_sizes, int n_in,
                              void* d_out, int out_size, void* d_ws, size_t ws_size,
                              hipStream_t stream) {
    const float* proposals = (const float*)d_in[2];
    const float* Wih0 = (const float*)d_in[4];
    const float* Whh0 = (const float*)d_in[5];
    const float* bih0 = (const float*)d_in[6];
    const float* bhh0 = (const float*)d_in[7];
    const float* Wih1 = (const float*)d_in[8];
    const float* Whh1 = (const float*)d_in[9];
    const float* bih1 = (const float*)d_in[10];
    const float* bhh1 = (const float*)d_in[11];
    const float* clsW = (const float*)d_in[12];
    const float* clsb = (const float*)d_in[13];
    const float* bbW  = (const float*)d_in[14];
    const float* bbb  = (const float*)d_in[15];

    char* ws = (char*)d_ws;
    const size_t XT_B  = 200ull * 32 * 256 * 16;    // 26,214,400
    const size_t H0_B  = 200ull * 128 * 256 * 16;   // 104,857,600
    const size_t H1_B  = 2ull * 128 * 256 * 16;     // 1,048,576
    const size_t C_B   = 512ull * 256 * 4;          // 524,288 each
    const size_t ARR_B = 4096;                      // 2 layers x 4 groups x 64 ints (256B stride)
    const size_t fixed = XT_B + H0_B + H1_B + 2 * C_B + ARR_B;
    const size_t xp_per_t = (size_t)G * 256 * 4;    // 2,097,152 per timestep

    size_t xp_avail = (ws_size > fixed) ? (ws_size - fixed) : 0;
    int TC = (int)(xp_avail / xp_per_t);
    if (TC > 200) TC = 200;
    if (TC < 1) TC = 1;

    float4* xT = (float4*)ws;
    float4* h0 = (float4*)(ws + XT_B);
    float4* h1 = (float4*)(ws + XT_B + H0_B);
    float*  c0 = (float*)(ws + XT_B + H0_B + H1_B);
    float*  c1 = (float*)(ws + XT_B + H0_B + H1_B + C_B);
    int*   arr = (int*)(ws + XT_B + H0_B + H1_B + 2 * C_B);
    float*  xp = (float*)(ws + fixed);

    hipMemsetAsync(arr, 0, ARR_B, stream);

    transpose_x<<<200, 256, 0, stream>>>((const float4*)proposals, xT);

    // layer 0: x = xT (K=128), h -> h0 (per-t slots, tmask=255)
    for (int t0 = 0; t0 < T_ALL; t0 += TC) {
        const int len = (TC < T_ALL - t0) ? TC : (T_ALL - t0);
        xproj_gemm<<<dim3(len, 4, 64), 256, 0, stream>>>(xT, Wih0, bih0, bhh0, xp, 32, t0);
        lstm_scan<<<dim3(64, 4), 256, 0, stream>>>(xp, Whh0, h0, c0, t0, t0 + len, 255, arr);
    }
    // layer 1: x = h0 (K=512), h -> h1 ping-pong (tmask=1)
    for (int t0 = 0; t0 < T_ALL; t0 += TC) {
        const int len = (TC < T_ALL - t0) ? TC : (T_ALL - t0);
        xproj_gemm<<<dim3(len, 4, 64), 256, 0, stream>>>((const float4*)h0, Wih1, bih1, bhh1, xp, 128, t0);
        lstm_scan<<<dim3(64, 4), 256, 0, stream>>>(xp, Whh1, h1, c1, t0, t0 + len, 1, arr + 1024);
    }

    // base_feat = h1 slot (199 & 1) = 1
    heads<<<256, 64, 0, stream>>>((const float4*)(h1 + 32768), (const float4*)clsW,
                                  clsb, (const float4*)bbW, bbb, (float*)d_out);
}

// Round 4
// 13182.623 us; speedup vs baseline: 2.8583x; 2.8583x over previous
//
#include <hip/hip_runtime.h>
#include <math.h>

#define T_ALL 200
#define G     2048
#define H     512
#define PW    132
#define PX    128

typedef __attribute__((address_space(1))) const unsigned int g_u32;
typedef __attribute__((address_space(3))) unsigned int l_u32;

// device-coherent (sc1) global->LDS async copy: reads the L3/coherence point,
// bypassing possibly-stale per-XCD L2.
__device__ __forceinline__ void gl2lds16_coh(const void* g, void* l) {
    __builtin_amdgcn_global_load_lds((g_u32*)g, (l_u32*)l, 16, 0, 16);
}

__device__ __forceinline__ float sigf(float x) { return 1.0f / (1.0f + expf(-x)); }

// proposals [b][t][c] -> xT[t][c/4][b] (float4 over c)
__global__ __launch_bounds__(256) void transpose_x(const float4* __restrict__ in,
                                                   float4* __restrict__ out) {
    const int t = blockIdx.x;
    const int b = threadIdx.x;
    #pragma unroll 4
    for (int cc = 0; cc < 32; ++cc) {
        out[((size_t)t * 32 + cc) * 256 + b] = in[((size_t)b * 200 + t) * 32 + cc];
    }
}

// Tiled fp32 GEMM: xp[tloc][r][b] = bias[r] + sum_k W[r][k] * x[slot][k][b]
// x: [slot][K4][256] float4-over-k. Block tile 128r x 128b, thread tile 8x8.
// grid (len, 2 bg, 16 rc), block 256.
__global__ __launch_bounds__(256, 2) void xproj_gemm(
    const float4* __restrict__ x, const float* __restrict__ W,
    const float* __restrict__ bih, const float* __restrict__ bhh,
    float* __restrict__ xp, int K4, int t0, int M)
{
    __shared__ float wl[2][32 * PW];
    __shared__ float xl[2][32 * PX];
    const int tloc = blockIdx.x;
    const int bg   = blockIdx.y;
    const int rc   = blockIdx.z;
    const int tid  = threadIdx.x;
    const int K    = K4 * 4;
    const int slot = (t0 + tloc) % M;
    const float4* xs = x + (size_t)slot * K4 * 256;
    const int rbase = rc * 128;
    const int bbase = bg * 128;

    const int bcol = tid & 15;
    const int rrow = tid >> 4;
    const int b0 = 4 * bcol, r0 = 4 * rrow;

    const int wr  = tid >> 3;          // +32*j
    const int wkq = tid & 7;
    const int xb  = tid & 127;
    const int xk4 = tid >> 7;          // +2*j

    float acc[8][8];
    #pragma unroll
    for (int i = 0; i < 8; ++i)
        #pragma unroll
        for (int j = 0; j < 8; ++j) acc[i][j] = 0.f;

    const int nk = K4 >> 3;            // 32-k rounds: 4 (K=128) or 16 (K=512)
    float4 wreg[4], xreg[4];

    // preload round 0
    #pragma unroll
    for (int j = 0; j < 4; ++j) {
        wreg[j] = *(const float4*)(W + (size_t)(rbase + wr + 32 * j) * K + wkq * 4);
        xreg[j] = xs[(size_t)(xk4 + 2 * j) * 256 + bbase + xb];
    }
    #pragma unroll
    for (int j = 0; j < 4; ++j) {
        #pragma unroll
        for (int i = 0; i < 4; ++i) {
            wl[0][(wkq * 4 + i) * PW + wr + 32 * j] = ((const float*)&wreg[j])[i];
            xl[0][((xk4 + 2 * j) * 4 + i) * PX + xb] = ((const float*)&xreg[j])[i];
        }
    }
    __syncthreads();

    for (int ro = 0; ro < nk; ++ro) {
        if (ro + 1 < nk) {
            const int k0 = (ro + 1) * 32;
            #pragma unroll
            for (int j = 0; j < 4; ++j) {
                wreg[j] = *(const float4*)(W + (size_t)(rbase + wr + 32 * j) * K + k0 + wkq * 4);
                xreg[j] = xs[(size_t)(k0 / 4 + xk4 + 2 * j) * 256 + bbase + xb];
            }
        }
        const float* wlb = wl[ro & 1];
        const float* xlb = xl[ro & 1];
        #pragma unroll 2
        for (int k = 0; k < 32; ++k) {
            const float4 w0 = *(const float4*)&wlb[k * PW + r0];
            const float4 w1 = *(const float4*)&wlb[k * PW + r0 + 64];
            const float4 v0 = *(const float4*)&xlb[k * PX + b0];
            const float4 v1 = *(const float4*)&xlb[k * PX + b0 + 64];
            const float wf[8] = {w0.x, w0.y, w0.z, w0.w, w1.x, w1.y, w1.z, w1.w};
            const float xf[8] = {v0.x, v0.y, v0.z, v0.w, v1.x, v1.y, v1.z, v1.w};
            #pragma unroll
            for (int i = 0; i < 8; ++i)
                #pragma unroll
                for (int j = 0; j < 8; ++j)
                    acc[i][j] += wf[i] * xf[j];
        }
        __syncthreads();
        if (ro + 1 < nk) {
            const int nb = (ro + 1) & 1;
            #pragma unroll
            for (int j = 0; j < 4; ++j) {
                #pragma unroll
                for (int i = 0; i < 4; ++i) {
                    wl[nb][(wkq * 4 + i) * PW + wr + 32 * j] = ((const float*)&wreg[j])[i];
                    xl[nb][((xk4 + 2 * j) * 4 + i) * PX + xb] = ((const float*)&xreg[j])[i];
                }
            }
            __syncthreads();
        }
    }

    #pragma unroll
    for (int ii = 0; ii < 8; ++ii) {
        const int rl = (ii < 4) ? (r0 + ii) : (r0 + 60 + ii);
        const int gr = rbase + rl;
        const float bias = bih[gr] + bhh[gr];
        float* o = xp + ((size_t)tloc * G + gr) * 256 + bbase;
        float4 u0 = {acc[ii][0] + bias, acc[ii][1] + bias, acc[ii][2] + bias, acc[ii][3] + bias};
        float4 u1 = {acc[ii][4] + bias, acc[ii][5] + bias, acc[ii][6] + bias, acc[ii][7] + bias};
        *(float4*)(o + b0) = u0;
        *(float4*)(o + b0 + 64) = u1;
    }
}

// Recurrent-only LSTM scan. grid (64, 4 bgroups), block 256 = 4 waves.
// Fence-free sync: h via relaxed agent stores (-> coherence point), barrier
// drains vmcnt, flag = relaxed agent store, wave0 spins on relaxed agent loads,
// h re-staged with sc1 global_load_lds. No L2 writeback/invalidate per step.
__global__ __launch_bounds__(256) void lstm_scan(
    const float* __restrict__ xp, const float* __restrict__ Wr,
    float4* hbase, float* __restrict__ cbuf,
    int t0, int t1, int M, int* arr_base)
{
    __shared__ float4 hs[2][2048];
    const int tid  = threadIdx.x;
    const int wv   = tid >> 6;
    const int lane = tid & 63;
    const int bi   = blockIdx.x;
    const int bg   = blockIdx.y;
    const int bG   = bg * 64 + lane;
    const int hid0 = __builtin_amdgcn_readfirstlane(bi * 8 + wv * 2);
    int* arr = arr_base + bg * 64;

    const float* wr[8];
    #pragma unroll
    for (int p = 0; p < 2; ++p)
        #pragma unroll
        for (int q = 0; q < 4; ++q)
            wr[p * 4 + q] = Wr + (size_t)(q * H + hid0 + p) * H;

    float c0, c1;
    if (t0 > 0) {
        c0 = cbuf[(size_t)hid0 * 256 + bG];
        c1 = cbuf[(size_t)(hid0 + 1) * 256 + bG];
    } else { c0 = 0.f; c1 = 0.f; }

    float a[8];
    {
        const float* xpt = xp;
        #pragma unroll
        for (int p = 0; p < 2; ++p)
            #pragma unroll
            for (int q = 0; q < 4; ++q)
                a[p * 4 + q] = xpt[(size_t)(q * H + hid0 + p) * 256 + bG];
    }

    for (int t = t0; t < t1; ++t) {
        if (t > 0) {
            const float4* hin = hbase + (size_t)((t - 1) % M) * 32768;
            #pragma unroll
            for (int j = 0; j < 8; ++j) {
                const int kk = wv + 4 * j;
                gl2lds16_coh(hin + (size_t)kk * 256 + bG, &hs[0][kk * 64]);
            }
            __syncthreads();
            for (int ro = 0; ro < 4; ++ro) {
                if (ro < 3) {
                    #pragma unroll
                    for (int j = 0; j < 8; ++j) {
                        const int kk = wv + 4 * j;
                        gl2lds16_coh(hin + (size_t)((ro + 1) * 32 + kk) * 256 + bG,
                                     &hs[(ro + 1) & 1][kk * 64]);
                    }
                }
                const float4* hb = hs[ro & 1];
                const int kbase = ro * 32;
                #pragma unroll 4
                for (int kk = 0; kk < 32; ++kk) {
                    const float4 v = hb[kk * 64 + lane];
                    const int ko = (kbase + kk) * 4;
                    #pragma unroll
                    for (int i = 0; i < 8; ++i) {
                        const float4 w = *(const float4*)(wr[i] + ko);
                        a[i] += w.x * v.x + w.y * v.y + w.z * v.z + w.w * v.w;
                    }
                }
                __syncthreads();
            }
        }

        float an[8];
        if (t + 1 < t1) {
            const float* xpt = xp + (size_t)(t + 1 - t0) * G * 256;
            #pragma unroll
            for (int p = 0; p < 2; ++p)
                #pragma unroll
                for (int q = 0; q < 4; ++q)
                    an[p * 4 + q] = xpt[(size_t)(q * H + hid0 + p) * 256 + bG];
        }

        const int slot = t % M;
        float* hw = (float*)(hbase + (size_t)slot * 32768);
        {
            const float ig = sigf(a[0]), fg = sigf(a[1]);
            const float gg = tanhf(a[2]), og = sigf(a[3]);
            c0 = fg * c0 + ig * gg;
            const float h = og * tanhf(c0);
            __hip_atomic_store(&hw[(((hid0 >> 2) * 256) + bG) * 4 + (hid0 & 3)], h,
                               __ATOMIC_RELAXED, __HIP_MEMORY_SCOPE_AGENT);
        }
        {
            const float ig = sigf(a[4]), fg = sigf(a[5]);
            const float gg = tanhf(a[6]), og = sigf(a[7]);
            c1 = fg * c1 + ig * gg;
            const float h = og * tanhf(c1);
            const int h1i = hid0 + 1;
            __hip_atomic_store(&hw[(((h1i >> 2) * 256) + bG) * 4 + (h1i & 3)], h,
                               __ATOMIC_RELAXED, __HIP_MEMORY_SCOPE_AGENT);
        }

        if (t + 1 < t1) {
            __threadfence_block();      // waitcnt-only drain, no cache ops
            __syncthreads();            // all 256 threads' h stores complete at L3
            if (tid == 0)
                __hip_atomic_store(&arr[bi], t + 1, __ATOMIC_RELAXED, __HIP_MEMORY_SCOPE_AGENT);
            if (wv == 0) {
                int v;
                do {
                    v = __hip_atomic_load(&arr[lane], __ATOMIC_RELAXED, __HIP_MEMORY_SCOPE_AGENT);
                } while (!__all(v >= t + 1));
            }
            __syncthreads();
        }

        #pragma unroll
        for (int i = 0; i < 8; ++i) a[i] = an[i];
    }

    cbuf[(size_t)hid0 * 256 + bG] = c0;
    cbuf[(size_t)(hid0 + 1) * 256 + bG] = c1;
}

// heads: base[k/4][b][4k] -> cls (256x40), bbox (256x2), 2 zero scalars
__global__ __launch_bounds__(64) void heads(
    const float4* __restrict__ base, const float4* __restrict__ clsW,
    const float* __restrict__ clsb, const float4* __restrict__ bbW,
    const float* __restrict__ bbb, float* __restrict__ out)
{
    const int b = blockIdx.x;
    const int j = threadIdx.x;
    if (j < 42) {
        const float4* w = (j < 40) ? (clsW + (size_t)j * 128) : (bbW + (size_t)(j - 40) * 128);
        float acc = 0.f;
        #pragma unroll 4
        for (int kk = 0; kk < 128; ++kk) {
            const float4 bv = base[(size_t)kk * 256 + b];
            const float4 wv = w[kk];
            acc += bv.x*wv.x + bv.y*wv.y + bv.z*wv.z + bv.w*wv.w;
        }
        if (j < 40) out[(size_t)b * 40 + j] = acc + clsb[j];
        else        out[10240 + (size_t)b * 2 + (j - 40)] = acc + bbb[j - 40];
    }
    if (b == 0 && (j == 62 || j == 63)) out[10752 + (j - 62)] = 0.f;
}

extern "C" void kernel_launch(void* const* d_in, const int* in_sizes, int n_in,
                              void* d_out, int out_size, void* d_ws, size_t ws_size,
                              hipStream_t stream) {
    const float* proposals = (const float*)d_in[2];
    const float* Wih0 = (const float*)d_in[4];
    const float* Whh0 = (const float*)d_in[5];
    const float* bih0 = (const float*)d_in[6];
    const float* bhh0 = (const float*)d_in[7];
    const float* Wih1 = (const float*)d_in[8];
    const float* Whh1 = (const float*)d_in[9];
    const float* bih1 = (const float*)d_in[10];
    const float* bhh1 = (const float*)d_in[11];
    const float* clsW = (const float*)d_in[12];
    const float* clsb = (const float*)d_in[13];
    const float* bbW  = (const float*)d_in[14];
    const float* bbb  = (const float*)d_in[15];

    char* ws = (char*)d_ws;
    const size_t XT_B  = 200ull * 32 * 256 * 16;   // 26,214,400
    const size_t H1_B  = 2ull * 32768 * 16;        // 1,048,576
    const size_t C_B   = 512ull * 256 * 4;         // 524,288 each
    const size_t ARR_B = 4096;
    const size_t HSLAB = 32768ull * 16;            // 524,288 per h0 ring slot
    const size_t XP_T  = (size_t)G * 256 * 4;      // 2,097,152 per timestep
    const size_t base  = XT_B + H1_B + 2 * C_B + ARR_B;

    // TC*(2*XP_T + HSLAB) + HSLAB <= ws - base
    long long avail = (long long)ws_size - (long long)base - (long long)HSLAB;
    int TC = avail > 0 ? (int)(avail / (long long)(2 * XP_T + HSLAB)) : 1;
    if (TC > 200) TC = 200;
    if (TC < 1) TC = 1;
    const int M0 = TC + 1;

    float4* xT  = (float4*)ws;
    float4* h1  = (float4*)(ws + XT_B);
    float*  c0  = (float*)(ws + XT_B + H1_B);
    float*  c1  = (float*)(ws + XT_B + H1_B + C_B);
    int*    arr = (int*)(ws + XT_B + H1_B + 2 * C_B);
    float*  xp0 = (float*)(ws + base);
    float*  xp1 = (float*)(ws + base + (size_t)TC * XP_T);
    float4* h0r = (float4*)(ws + base + 2 * (size_t)TC * XP_T);

    hipMemsetAsync(arr, 0, ARR_B, stream);

    transpose_x<<<200, 256, 0, stream>>>((const float4*)proposals, xT);

    for (int t0 = 0; t0 < T_ALL; t0 += TC) {
        const int len = (TC < T_ALL - t0) ? TC : (T_ALL - t0);
        // layer 0: x = xT (K=128, direct t addressing via huge M)
        xproj_gemm<<<dim3(len, 2, 16), 256, 0, stream>>>(xT, Wih0, bih0, bhh0,
                                                         xp0, 32, t0, 1 << 30);
        lstm_scan<<<dim3(64, 4), 256, 0, stream>>>(xp0, Whh0, h0r, c0,
                                                   t0, t0 + len, M0, arr);
        // layer 1: x = h0 ring (K=512)
        xproj_gemm<<<dim3(len, 2, 16), 256, 0, stream>>>((const float4*)h0r, Wih1,
                                                         bih1, bhh1, xp1, 128, t0, M0);
        lstm_scan<<<dim3(64, 4), 256, 0, stream>>>(xp1, Whh1, h1, c1,
                                                   t0, t0 + len, 2, arr + 256);
    }

    // base_feat = h1 slot (199 % 2) = 1
    heads<<<256, 64, 0, stream>>>((const float4*)(h1 + 32768), (const float4*)clsW,
                                  clsb, (const float4*)bbW, bbb, (float*)d_out);
}